// Round 8
// baseline (297.588 us; speedup 1.0000x reference)
//
#include <hip/hip_runtime.h>
#include <stdint.h>

typedef unsigned int u32;
typedef unsigned long long u64;

// key = ((b*512 + z/2)*512 + y/2)*512 + x/2  in [0, 2^29)
// rec = (key<<3)|off. coarse = rec>>24 (8b), fine = (rec>>17)&127 (7b),
// bucket = key>>14 = rec>>17 (15b), local key = key & 0x3FFF (14b).
#define LBITS  14
#define LMASK  ((1u << LBITS) - 1u)
#define NBUCK  (1u << (29 - LBITS))      // 32768 fine buckets
#define BWORDS (1u << (LBITS - 5))       // 512 u32 bitmap words / bucket
#define WPL    (BWORDS / 64)             // 8 words per lane (one prefix group)
#define WOPAD  (BWORDS + BWORDS / 32)    // +1 word per 32 -> conflict-free strided access
#define FCAP   192                       // LDS feats slots per bucket (mean uc ~122)
#define BPB    4                         // buckets (waves) per 256-thr block
#define TILE_A 8192                      // phase_a / part1 tile (32 rec/thread)
#define RPT    (TILE_A / 256)            // records per thread in part1 (32)
#define S2     2                         // chunks per coarse bucket in part2
#define CAP2   9216                      // part2 LDS stage capacity (chunk ~7812, +16sigma)
#define RPT2   (CAP2 / 256)              // 36
#define RECV   4                         // pass_emit register-cached records/lane
#define CAP    224                       // fixed buckrec window per bucket (max cnt ~172)
#define SCAN_ELEM 2048

__device__ __forceinline__ u32 woidx(u32 w) { return w + (w >> 5); }

// wave64 is lockstep on CDNA: intra-wave LDS producer->consumer needs only a
// drained LDS counter, not a block barrier.
__device__ __forceinline__ void wsync() {
    asm volatile("s_waitcnt lgkmcnt(0)" ::: "memory");
}

__device__ __forceinline__ u32 make_key(int4 c) {
    return ((((u32)c.x * 512u + ((u32)c.w >> 1)) * 512u + ((u32)c.z >> 1)) * 512u)
           + ((u32)c.y >> 1);
}

// ---- phase A: coords -> linrec + per-tile coarse histogram (bin-major matrix)
__global__ void __launch_bounds__(256) phase_a(const int4* __restrict__ coords,
        u32* __restrict__ linrec, u32* __restrict__ histmat, int n, u32 NT) {
    __shared__ u32 h[4 * 256];
    u32 t = threadIdx.x, wave = t >> 6;
    for (u32 j = t; j < 1024u; j += 256u) h[j] = 0u;
    __syncthreads();
    u32 base = blockIdx.x * TILE_A;
    u32 m = min((u32)TILE_A, (u32)n - base);
    for (u32 j = t; j < m; j += 256u) {
        int4 c = coords[base + j];
        u32 key = make_key(c);
        u32 off = ((u32)c.y & 1u) | (((u32)c.z & 1u) << 1) | (((u32)c.w & 1u) << 2);
        u32 rec = (key << 3) | off;
        linrec[base + j] = rec;
        atomicAdd(&h[wave * 256u + (rec >> 24)], 1u);
    }
    __syncthreads();
    histmat[t * NT + blockIdx.x] = h[t] + h[256u + t] + h[512u + t] + h[768u + t];
}

// ---- one-kernel exclusive scan: block b reduces data[0..b*2048) directly,
// then applies its own chunk. Writes to SEPARATE out (no in-place race).
__global__ void scan_one(const u32* __restrict__ data, u32* __restrict__ out,
                         u32 G, u32 NB, u32* __restrict__ total) {
    __shared__ u32 s[256];
    __shared__ u32 pb;
    u32 t = threadIdx.x;
    u32 pred = blockIdx.x * SCAN_ELEM;
    u32 sum0 = 0;
    for (u32 i = t; i < pred; i += 256u) sum0 += data[i];
    s[t] = sum0; __syncthreads();
    for (int d = 128; d > 0; d >>= 1) { if ((int)t < d) s[t] += s[t + d]; __syncthreads(); }
    if (t == 0) pb = s[0];
    __syncthreads();
    u32 base = pred + t * 8u;
    u32 v[8]; u32 sum = 0;
    #pragma unroll
    for (int j = 0; j < 8; ++j) {
        u32 idx = base + j;
        v[j] = (idx < G) ? data[idx] : 0u;
        sum += v[j];
    }
    s[t] = sum; __syncthreads();
    for (int d = 1; d < 256; d <<= 1) {
        u32 add = (t >= (u32)d) ? s[t - d] : 0u;
        __syncthreads(); s[t] += add; __syncthreads();
    }
    u32 run = s[t] - sum + pb;
    #pragma unroll
    for (int j = 0; j < 8; ++j) {
        u32 idx = base + j;
        if (idx < G) { u32 x = v[j]; out[idx] = run; run += x; }
    }
    if (total && blockIdx.x == NB - 1u && t == 255u) total[0] = pb + s[255];
}

// ---- part1: coarse scatter via LDS staging, uint4 loads; also zeroes cursor
__global__ void __launch_bounds__(256) part1(const u32* __restrict__ linrec,
        const u32* __restrict__ histex, u32* __restrict__ tmp,
        u32* __restrict__ cursor, int n, u32 NT) {
    __shared__ u32 stage[TILE_A];
    __shared__ u32 lcur[256];
    __shared__ u32 gb[256];
    __shared__ u32 wtot[4];
    u32 t = threadIdx.x, wave = t >> 6, lane = t & 63u;
    if (blockIdx.x < 128u) cursor[blockIdx.x * 256u + t] = 0u;  // NBUCK cursors
    u32 base = blockIdx.x * TILE_A;
    u32 m = min((u32)TILE_A, (u32)n - base);
    u32 m4 = m >> 2, rem = m & 3u;
    lcur[t] = 0u;
    __syncthreads();
    u32 recv[RPT]; u32 tailrec = 0u;
    const uint4* lr4 = (const uint4*)(linrec + base);
    #pragma unroll
    for (int k = 0; k < RPT / 4; ++k) {
        u32 j4 = (u32)k * 256u + t;
        if (j4 < m4) {
            uint4 v = lr4[j4];
            recv[k * 4 + 0] = v.x; recv[k * 4 + 1] = v.y;
            recv[k * 4 + 2] = v.z; recv[k * 4 + 3] = v.w;
            atomicAdd(&lcur[v.x >> 24], 1u);
            atomicAdd(&lcur[v.y >> 24], 1u);
            atomicAdd(&lcur[v.z >> 24], 1u);
            atomicAdd(&lcur[v.w >> 24], 1u);
        }
    }
    if (t < rem) {
        tailrec = linrec[base + (m & ~3u) + t];
        atomicAdd(&lcur[tailrec >> 24], 1u);
    }
    __syncthreads();
    // 256-bin exclusive scan: wave-local prefix + cross-wave offset
    u32 v = lcur[t];
    u32 incl = v;
    #pragma unroll
    for (int d = 1; d < 64; d <<= 1) {
        u32 x = __shfl_up(incl, d);
        if ((int)lane >= d) incl += x;
    }
    if (lane == 63u) wtot[wave] = incl;
    __syncthreads();
    u32 off = (wave > 0u ? wtot[0] : 0u) + (wave > 1u ? wtot[1] : 0u)
            + (wave > 2u ? wtot[2] : 0u);
    u32 excl = off + incl - v;
    lcur[t] = excl;                        // local place cursor
    gb[t] = histex[t * NT + blockIdx.x] - excl;   // dst = gb[bin] + stage_idx
    __syncthreads();
    #pragma unroll
    for (int k = 0; k < RPT / 4; ++k) {
        u32 j4 = (u32)k * 256u + t;
        if (j4 < m4) {
            #pragma unroll
            for (int e = 0; e < 4; ++e) {
                u32 rec = recv[k * 4 + e];
                u32 pos = atomicAdd(&lcur[rec >> 24], 1u);
                stage[pos] = rec;
            }
        }
    }
    if (t < rem) {
        u32 pos = atomicAdd(&lcur[tailrec >> 24], 1u);
        stage[pos] = tailrec;
    }
    __syncthreads();
    for (u32 j = t; j < m; j += 256u) {
        u32 rec = stage[j];
        tmp[gb[rec >> 24] + j] = rec;      // runs of ~32 -> full-line writes
    }
}

// ---- part2: fine scatter into fixed per-bucket windows; bulk atomic reserve
__global__ void __launch_bounds__(256) part2(const u32* __restrict__ tmp,
        const u32* __restrict__ histex, u32* __restrict__ cursor,
        u32* __restrict__ buckrec, int n, u32 NT) {
    __shared__ u32 stage[CAP2];
    __shared__ u32 lcur[128];
    __shared__ u32 dstb[128];
    __shared__ u32 wtot[2];
    u32 t = threadIdx.x, lane = t & 63u;
    u32 c = blockIdx.x / S2, s = blockIdx.x % S2;
    u32 cs = histex[c * NT];
    u32 ce = (c == 255u) ? (u32)n : histex[(c + 1u) * NT];
    u32 L = ce - cs;
    u32 lo = cs + L * s / S2, hi = cs + L * (s + 1u) / S2;
    u32 cnt = hi - lo;
    if (cnt <= (u32)CAP2) {
        if (t < 128u) lcur[t] = 0u;
        __syncthreads();
        u32 recv[RPT2];
        #pragma unroll
        for (int k = 0; k < RPT2; ++k) {
            u32 j = (u32)k * 256u + t;
            if (j < cnt) {
                u32 rec = tmp[lo + j];
                recv[k] = rec;
                atomicAdd(&lcur[(rec >> 17) & 127u], 1u);
            }
        }
        __syncthreads();
        u32 v = 0, incl = 0;
        if (t < 128u) {
            v = lcur[t];
            incl = v;
            #pragma unroll
            for (int d = 1; d < 64; d <<= 1) {
                u32 x = __shfl_up(incl, d);
                if ((int)lane >= d) incl += x;
            }
            if (lane == 63u) wtot[t >> 6] = incl;
        }
        __syncthreads();
        if (t < 128u) {
            u32 off = (t >= 64u) ? wtot[0] : 0u;
            u32 excl = off + incl - v;
            u32 bucket = (c << 7) | t;
            u32 gbase = atomicAdd(&cursor[bucket], v);   // reserve v slots (one per bin)
            lcur[t] = excl;
            dstb[t] = bucket * (u32)CAP + gbase - excl;
        }
        __syncthreads();
        #pragma unroll
        for (int k = 0; k < RPT2; ++k) {
            u32 j = (u32)k * 256u + t;
            if (j < cnt) {
                u32 rec = recv[k];
                u32 pos = atomicAdd(&lcur[(rec >> 17) & 127u], 1u);
                stage[pos] = rec;
            }
        }
        __syncthreads();
        for (u32 j = t; j < cnt; j += 256u) {
            u32 rec = stage[j];
            buckrec[dstb[(rec >> 17) & 127u] + j] = rec;   // runs ~61 -> coalesced
        }
    } else {
        // fallback: direct atomic scatter into windows (rare)
        for (u32 i = lo + t; i < hi; i += 256u) {
            u32 rec = tmp[i];
            u32 b = rec >> 17;
            u32 pos = atomicAdd(&cursor[b], 1u);
            buckrec[b * (u32)CAP + pos] = rec;
        }
    }
}

// ---- one wave per fine bucket, no block barriers: bitmap -> unique count
__global__ void __launch_bounds__(256) pass_count(const u32* __restrict__ buckrec,
        const u32* __restrict__ bcnt, u32* __restrict__ ucount, int n) {
    __shared__ u32 bm[BPB][WOPAD];
    u32 wave = threadIdx.x >> 6, lane = threadIdx.x & 63u;
    u32 bucket = blockIdx.x * BPB + wave;
    u32* B = bm[wave];
    #pragma unroll
    for (int j = 0; j < WPL; ++j) B[woidx(lane * WPL + j)] = 0u;
    wsync();
    u32 start = bucket * (u32)CAP;
    u32 end = start + bcnt[bucket];
    for (u32 i = start + lane; i < end; i += 64u) {
        u32 lk = (buckrec[i] >> 3) & LMASK;
        atomicOr(&B[woidx(lk >> 5)], 1u << (lk & 31u));
    }
    wsync();
    u32 sum = 0;
    #pragma unroll
    for (int j = 0; j < WPL; ++j) sum += __popc(B[woidx(lane * WPL + j)]);
    #pragma unroll
    for (int d = 1; d < 64; d <<= 1) sum += __shfl_xor(sum, d);
    if (lane == 0u) ucount[bucket] = sum;
}

// ---- one wave per fine bucket, no block barriers: rank table + feats + emit
// records register-cached (RECV/lane covers cnt<=256 = CAP; fallback loop dead)
__global__ void __launch_bounds__(256) pass_emit(const u32* __restrict__ buckrec,
        const u32* __restrict__ bcnt, const u32* __restrict__ ubase,
        const float* __restrict__ kern, float4* __restrict__ rows,
        float* __restrict__ feats, int n) {
    __shared__ u32 bm[BPB][WOPAD];
    __shared__ u32 wofW[BPB][BWORDS];     // per-WORD excl unique prefix, j-major (j<<6)|lane
    __shared__ float fl[BPB][FCAP];
    __shared__ float ksc[BPB][8];
    u32 wave = threadIdx.x >> 6, lane = threadIdx.x & 63u;
    u32 bucket = blockIdx.x * BPB + wave;
    u32* B = bm[wave];
    u32* W = wofW[wave];
    float* F = fl[wave];
    #pragma unroll
    for (int j = 0; j < WPL; ++j) B[woidx(lane * WPL + j)] = 0u;
    #pragma unroll
    for (u32 j = lane; j < FCAP; j += 64u) F[j] = 0.f;
    if (lane < 8u) ksc[wave][lane] = (float)(1u << lane) * kern[lane];
    wsync();
    u32 start = bucket * (u32)CAP;
    u32 cnt = bcnt[bucket];
    u32 recv[RECV];
    #pragma unroll
    for (int k = 0; k < RECV; ++k) {
        u32 idx = (u32)k * 64u + lane;
        if (idx < cnt) {
            u32 rec = buckrec[start + idx];
            recv[k] = rec;
            u32 lk = (rec >> 3) & LMASK;
            atomicOr(&B[woidx(lk >> 5)], 1u << (lk & 31u));
        }
    }
    wsync();
    u32 wv[WPL]; u32 pc[WPL]; u32 sum = 0;
    #pragma unroll
    for (int j = 0; j < WPL; ++j) {
        wv[j] = B[woidx(lane * WPL + j)];
        pc[j] = __popc(wv[j]);
        sum += pc[j];
    }
    u32 incl = sum;
    #pragma unroll
    for (int d = 1; d < 64; d <<= 1) {
        u32 tt = __shfl_up(incl, d);
        if ((int)lane >= d) incl += tt;
    }
    u32 lex = incl - sum;                 // lane-exclusive unique offset in bucket
    u32 uc = __shfl(incl, 63);            // bucket total uniques
    {
        u32 r = lex;
        #pragma unroll
        for (int j = 0; j < WPL; ++j) { W[((u32)j << 6) | lane] = r; r += pc[j]; }
    }
    wsync();
    u32 base = ubase[bucket];
    bool lds_ok = (uc <= FCAP);
    if (!lds_ok) {                        // rare: zero own global window first
        for (u32 j = lane; j < uc; j += 64u) feats[base + j] = 0.f;
        asm volatile("s_waitcnt vmcnt(0)" ::: "memory");
    }
    #pragma unroll
    for (int k = 0; k < RECV; ++k) {
        u32 idx = (u32)k * 64u + lane;
        if (idx < cnt) {
            u32 rec = recv[k];
            float contrib = ksc[wave][rec & 7u];
            u32 lk = (rec >> 3) & LMASK;
            u32 w = lk >> 5, bit = lk & 31u;
            u32 r = W[((w & 7u) << 6) | (w >> 3)]
                  + __popc(B[woidx(w)] & ((1u << bit) - 1u));
            if (lds_ok) atomicAdd(&F[r], contrib);
            else        atomicAdd(&feats[base + r], contrib);
        }
    }
    wsync();
    u32 rank = base + lex;
    u32 keyhi = bucket << LBITS;
    #pragma unroll
    for (int j = 0; j < WPL; ++j) {
        u32 bits = wv[j];
        u32 kb = keyhi | ((lane * (u32)WPL + (u32)j) << 5);
        while (bits) {
            u32 tz = __builtin_ctz(bits);
            bits &= bits - 1u;
            u32 key = kb | tz;
            rows[rank++] = make_float4((float)(key >> 27), (float)(key & 511u),
                                       (float)((key >> 9) & 511u),
                                       (float)((key >> 18) & 511u));
        }
    }
    if (lds_ok) {
        for (u32 j = lane; j < uc; j += 64u) feats[base + j] = F[j];
    }
}

// pad rows AND feats in [U, n): feats is not globally pre-zeroed
__global__ void pad_fill(float4* __restrict__ rows, float* __restrict__ feats,
                         const u32* __restrict__ counter, int n) {
    int i = blockIdx.x * blockDim.x + threadIdx.x;
    if (i < n && (u32)i >= counter[0]) {
        rows[i] = make_float4(-1.f, -1.f, -1.f, -1.f);
        feats[i] = 0.f;
    }
}

extern "C" void kernel_launch(void* const* d_in, const int* in_sizes, int n_in,
                              void* d_out, int out_size, void* d_ws, size_t ws_size,
                              hipStream_t stream) {
    const int n = in_sizes[0] / 4;               // 4,000,000 points
    const int4* coords = (const int4*)d_in[0];
    const float* kern  = (const float*)d_in[1];
    const u32 NT = ((u32)n + TILE_A - 1) / TILE_A;        // 489 tiles
    const u32 G1 = 256 * NT;                               // histmat entries (125184)
    const u32 NB1 = (G1 + SCAN_ELEM - 1) / SCAN_ELEM;      // 62
    const u32 NB3 = (NBUCK + SCAN_ELEM - 1) / SCAN_ELEM;   // 16

    u32* wsp = (u32*)d_ws;
    u32* tmp     = wsp;                    // n  (coarse-ordered records)
    u32* histmat = tmp + n;                // G1 raw per-tile hist
    u32* histex  = histmat + G1;           // G1 scanned bases
    u32* cursor  = histex + G1;            // NBUCK (zeroed in part1 -> counts after part2)
    u32* ucount  = cursor + NBUCK;         // NBUCK raw unique counts
    u32* ubase   = ucount + NBUCK;         // NBUCK scanned bases
    u32* counter = ubase + NBUCK;          // 4
    u32* linrec  = counter + 4;            // n (dead after part1)
    u32* buckrec = linrec;                 // NBUCK*CAP windows, overlaps linrec

    float4* rows  = (float4*)d_out;                              // n rows
    float*  feats = (float*)((char*)d_out + (size_t)n * 16);     // n fp32

    phase_a<<<NT, 256, 0, stream>>>(coords, linrec, histmat, n, NT);
    scan_one<<<NB1, 256, 0, stream>>>(histmat, histex, G1, NB1, (u32*)nullptr);
    part1<<<NT, 256, 0, stream>>>(linrec, histex, tmp, cursor, n, NT);
    part2<<<256 * S2, 256, 0, stream>>>(tmp, histex, cursor, buckrec, n, NT);
    pass_count<<<NBUCK / BPB, 256, 0, stream>>>(buckrec, cursor, ucount, n);
    scan_one<<<NB3, 256, 0, stream>>>(ucount, ubase, NBUCK, NB3, counter);
    pass_emit<<<NBUCK / BPB, 256, 0, stream>>>(buckrec, cursor, ubase, kern,
                                               rows, feats, n);
    pad_fill<<<((u32)n + 255) / 256, 256, 0, stream>>>(rows, feats, counter, n);
}

// Round 9
// 227.871 us; speedup vs baseline: 1.3059x; 1.3059x over previous
//
#include <hip/hip_runtime.h>
#include <stdint.h>

typedef unsigned int u32;
typedef unsigned long long u64;

// key = ((b*512 + z/2)*512 + y/2)*512 + x/2  in [0, 2^29)
// rec = (key<<3)|off. coarse = rec>>24 (8b), fine = (rec>>17)&127 (7b),
// bucket = key>>14 = rec>>17 (15b), local key = key & 0x3FFF (14b).
#define LBITS  14
#define LMASK  ((1u << LBITS) - 1u)
#define NBUCK  (1u << (29 - LBITS))      // 32768 fine buckets
#define BWORDS (1u << (LBITS - 5))       // 512 u32 bitmap words / bucket
#define WPL    (BWORDS / 64)             // 8 words per lane (one prefix group)
#define WOPAD  (BWORDS + BWORDS / 32)    // +1 word per 32 -> conflict-free strided access
#define FCAP   192                       // LDS feats slots per bucket (mean uc ~122)
#define BPB    4                         // buckets (waves) per 256-thr block
#define TILE_A 8192                      // phase_a / part1 tile (32 rec/thread)
#define RPT    (TILE_A / 256)            // records per thread in part1 (32)
#define S2     2                         // chunks per coarse bucket in part2
#define CAP2   9216                      // part2 LDS stage capacity (chunk ~7812, +16sigma)
#define RPT2   (CAP2 / 256)              // 36
#define RECV   4                         // pass_emit register-cached records/lane
#define CAP    224                       // fixed buckrec window per bucket (max cnt ~172)
#define SCAN_ELEM 2048

__device__ __forceinline__ u32 woidx(u32 w) { return w + (w >> 5); }

// wave64 is lockstep on CDNA: intra-wave LDS producer->consumer needs only a
// drained LDS counter, not a block barrier.
__device__ __forceinline__ void wsync() {
    asm volatile("s_waitcnt lgkmcnt(0)" ::: "memory");
}

__device__ __forceinline__ u32 make_key(int4 c) {
    return ((((u32)c.x * 512u + ((u32)c.w >> 1)) * 512u + ((u32)c.z >> 1)) * 512u)
           + ((u32)c.y >> 1);
}

// ---- phase A: coords -> linrec + per-tile coarse histogram (bin-major matrix)
__global__ void __launch_bounds__(256) phase_a(const int4* __restrict__ coords,
        u32* __restrict__ linrec, u32* __restrict__ histmat, int n, u32 NT) {
    __shared__ u32 h[4 * 256];
    u32 t = threadIdx.x, wave = t >> 6;
    for (u32 j = t; j < 1024u; j += 256u) h[j] = 0u;
    __syncthreads();
    u32 base = blockIdx.x * TILE_A;
    u32 m = min((u32)TILE_A, (u32)n - base);
    for (u32 j = t; j < m; j += 256u) {
        int4 c = coords[base + j];
        u32 key = make_key(c);
        u32 off = ((u32)c.y & 1u) | (((u32)c.z & 1u) << 1) | (((u32)c.w & 1u) << 2);
        u32 rec = (key << 3) | off;
        linrec[base + j] = rec;
        atomicAdd(&h[wave * 256u + (rec >> 24)], 1u);
    }
    __syncthreads();
    histmat[t * NT + blockIdx.x] = h[t] + h[256u + t] + h[512u + t] + h[768u + t];
}

// ---- scan step 1: per-chunk raw sums ----
__global__ void scan_reduce(const u32* __restrict__ data, u32* __restrict__ partial, u32 G) {
    __shared__ u32 s[256];
    u32 t = threadIdx.x;
    u32 base = blockIdx.x * SCAN_ELEM + t * 8u;
    u32 sum = 0;
    #pragma unroll
    for (int j = 0; j < 8; ++j) { u32 idx = base + j; if (idx < G) sum += data[idx]; }
    s[t] = sum; __syncthreads();
    for (int d = 128; d > 0; d >>= 1) { if ((int)t < d) s[t] += s[t + d]; __syncthreads(); }
    if (t == 0) partial[blockIdx.x] = s[0];
}

// ---- scan step 2: apply with inline top-level reduction of raw partials ----
// base(block b) = sum of partial[0..b). Last block optionally writes grand total.
__global__ void scan_apply2(const u32* __restrict__ data, u32* __restrict__ out,
                            const u32* __restrict__ partial, u32 G, u32 NB,
                            u32* __restrict__ total) {
    __shared__ u32 s[256];
    __shared__ u32 pb[2];
    u32 t = threadIdx.x;
    u32 p = (t < NB) ? partial[t] : 0u;
    u32 pbef = (t < blockIdx.x) ? p : 0u;
    s[t] = pbef; __syncthreads();
    for (int d = 128; d > 0; d >>= 1) { if ((int)t < d) s[t] += s[t + d]; __syncthreads(); }
    if (t == 0) pb[0] = s[0];
    __syncthreads();
    if (total) {
        s[t] = p; __syncthreads();
        for (int d = 128; d > 0; d >>= 1) { if ((int)t < d) s[t] += s[t + d]; __syncthreads(); }
        if (t == 0) pb[1] = s[0];
        __syncthreads();
        if (blockIdx.x == NB - 1u && t == 0u) total[0] = pb[1];
    }
    u32 base = blockIdx.x * SCAN_ELEM + t * 8u;
    u32 v[8]; u32 sum = 0;
    #pragma unroll
    for (int j = 0; j < 8; ++j) {
        u32 idx = base + j;
        v[j] = (idx < G) ? data[idx] : 0u;
        sum += v[j];
    }
    s[t] = sum; __syncthreads();
    for (int d = 1; d < 256; d <<= 1) {
        u32 add = (t >= (u32)d) ? s[t - d] : 0u;
        __syncthreads(); s[t] += add; __syncthreads();
    }
    u32 run = s[t] - sum + pb[0];
    #pragma unroll
    for (int j = 0; j < 8; ++j) {
        u32 idx = base + j;
        if (idx < G) { u32 x = v[j]; out[idx] = run; run += x; }
    }
}

// ---- part1: coarse scatter via LDS staging, uint4 loads; also zeroes cursor
__global__ void __launch_bounds__(256) part1(const u32* __restrict__ linrec,
        const u32* __restrict__ histex, u32* __restrict__ tmp,
        u32* __restrict__ cursor, int n, u32 NT) {
    __shared__ u32 stage[TILE_A];
    __shared__ u32 lcur[256];
    __shared__ u32 gb[256];
    __shared__ u32 wtot[4];
    u32 t = threadIdx.x, wave = t >> 6, lane = t & 63u;
    if (blockIdx.x < 128u) cursor[blockIdx.x * 256u + t] = 0u;  // NBUCK cursors
    u32 base = blockIdx.x * TILE_A;
    u32 m = min((u32)TILE_A, (u32)n - base);
    u32 m4 = m >> 2, rem = m & 3u;
    lcur[t] = 0u;
    __syncthreads();
    u32 recv[RPT]; u32 tailrec = 0u;
    const uint4* lr4 = (const uint4*)(linrec + base);
    #pragma unroll
    for (int k = 0; k < RPT / 4; ++k) {
        u32 j4 = (u32)k * 256u + t;
        if (j4 < m4) {
            uint4 v = lr4[j4];
            recv[k * 4 + 0] = v.x; recv[k * 4 + 1] = v.y;
            recv[k * 4 + 2] = v.z; recv[k * 4 + 3] = v.w;
            atomicAdd(&lcur[v.x >> 24], 1u);
            atomicAdd(&lcur[v.y >> 24], 1u);
            atomicAdd(&lcur[v.z >> 24], 1u);
            atomicAdd(&lcur[v.w >> 24], 1u);
        }
    }
    if (t < rem) {
        tailrec = linrec[base + (m & ~3u) + t];
        atomicAdd(&lcur[tailrec >> 24], 1u);
    }
    __syncthreads();
    // 256-bin exclusive scan: wave-local prefix + cross-wave offset
    u32 v = lcur[t];
    u32 incl = v;
    #pragma unroll
    for (int d = 1; d < 64; d <<= 1) {
        u32 x = __shfl_up(incl, d);
        if ((int)lane >= d) incl += x;
    }
    if (lane == 63u) wtot[wave] = incl;
    __syncthreads();
    u32 off = (wave > 0u ? wtot[0] : 0u) + (wave > 1u ? wtot[1] : 0u)
            + (wave > 2u ? wtot[2] : 0u);
    u32 excl = off + incl - v;
    lcur[t] = excl;                        // local place cursor
    gb[t] = histex[t * NT + blockIdx.x] - excl;   // dst = gb[bin] + stage_idx
    __syncthreads();
    #pragma unroll
    for (int k = 0; k < RPT / 4; ++k) {
        u32 j4 = (u32)k * 256u + t;
        if (j4 < m4) {
            #pragma unroll
            for (int e = 0; e < 4; ++e) {
                u32 rec = recv[k * 4 + e];
                u32 pos = atomicAdd(&lcur[rec >> 24], 1u);
                stage[pos] = rec;
            }
        }
    }
    if (t < rem) {
        u32 pos = atomicAdd(&lcur[tailrec >> 24], 1u);
        stage[pos] = tailrec;
    }
    __syncthreads();
    for (u32 j = t; j < m; j += 256u) {
        u32 rec = stage[j];
        tmp[gb[rec >> 24] + j] = rec;      // runs of ~32 -> full-line writes
    }
}

// ---- part2: fine scatter into fixed per-bucket windows; bulk atomic reserve
__global__ void __launch_bounds__(256) part2(const u32* __restrict__ tmp,
        const u32* __restrict__ histex, u32* __restrict__ cursor,
        u32* __restrict__ buckrec, int n, u32 NT) {
    __shared__ u32 stage[CAP2];
    __shared__ u32 lcur[128];
    __shared__ u32 dstb[128];
    __shared__ u32 wtot[2];
    u32 t = threadIdx.x, lane = t & 63u;
    u32 c = blockIdx.x / S2, s = blockIdx.x % S2;
    u32 cs = histex[c * NT];
    u32 ce = (c == 255u) ? (u32)n : histex[(c + 1u) * NT];
    u32 L = ce - cs;
    u32 lo = cs + L * s / S2, hi = cs + L * (s + 1u) / S2;
    u32 cnt = hi - lo;
    if (cnt <= (u32)CAP2) {
        if (t < 128u) lcur[t] = 0u;
        __syncthreads();
        u32 recv[RPT2];
        #pragma unroll
        for (int k = 0; k < RPT2; ++k) {
            u32 j = (u32)k * 256u + t;
            if (j < cnt) {
                u32 rec = tmp[lo + j];
                recv[k] = rec;
                atomicAdd(&lcur[(rec >> 17) & 127u], 1u);
            }
        }
        __syncthreads();
        u32 v = 0, incl = 0;
        if (t < 128u) {
            v = lcur[t];
            incl = v;
            #pragma unroll
            for (int d = 1; d < 64; d <<= 1) {
                u32 x = __shfl_up(incl, d);
                if ((int)lane >= d) incl += x;
            }
            if (lane == 63u) wtot[t >> 6] = incl;
        }
        __syncthreads();
        if (t < 128u) {
            u32 off = (t >= 64u) ? wtot[0] : 0u;
            u32 excl = off + incl - v;
            u32 bucket = (c << 7) | t;
            u32 gbase = atomicAdd(&cursor[bucket], v);   // reserve v slots (one per bin)
            lcur[t] = excl;
            dstb[t] = bucket * (u32)CAP + gbase - excl;
        }
        __syncthreads();
        #pragma unroll
        for (int k = 0; k < RPT2; ++k) {
            u32 j = (u32)k * 256u + t;
            if (j < cnt) {
                u32 rec = recv[k];
                u32 pos = atomicAdd(&lcur[(rec >> 17) & 127u], 1u);
                stage[pos] = rec;
            }
        }
        __syncthreads();
        for (u32 j = t; j < cnt; j += 256u) {
            u32 rec = stage[j];
            buckrec[dstb[(rec >> 17) & 127u] + j] = rec;   // runs ~61 -> coalesced
        }
    } else {
        // fallback: direct atomic scatter into windows (rare)
        for (u32 i = lo + t; i < hi; i += 256u) {
            u32 rec = tmp[i];
            u32 b = rec >> 17;
            u32 pos = atomicAdd(&cursor[b], 1u);
            buckrec[b * (u32)CAP + pos] = rec;
        }
    }
}

// ---- one wave per fine bucket, no block barriers: bitmap -> unique count
__global__ void __launch_bounds__(256) pass_count(const u32* __restrict__ buckrec,
        const u32* __restrict__ bcnt, u32* __restrict__ ucount, int n) {
    __shared__ u32 bm[BPB][WOPAD];
    u32 wave = threadIdx.x >> 6, lane = threadIdx.x & 63u;
    u32 bucket = blockIdx.x * BPB + wave;
    u32* B = bm[wave];
    #pragma unroll
    for (int j = 0; j < WPL; ++j) B[woidx(lane * WPL + j)] = 0u;
    wsync();
    u32 start = bucket * (u32)CAP;
    u32 end = start + bcnt[bucket];
    for (u32 i = start + lane; i < end; i += 64u) {
        u32 lk = (buckrec[i] >> 3) & LMASK;
        atomicOr(&B[woidx(lk >> 5)], 1u << (lk & 31u));
    }
    wsync();
    u32 sum = 0;
    #pragma unroll
    for (int j = 0; j < WPL; ++j) sum += __popc(B[woidx(lane * WPL + j)]);
    #pragma unroll
    for (int d = 1; d < 64; d <<= 1) sum += __shfl_xor(sum, d);
    if (lane == 0u) ucount[bucket] = sum;
}

// ---- one wave per fine bucket, no block barriers: rank table + feats + emit
// records register-cached (RECV/lane covers cnt<=256 = CAP; fallback loop dead)
__global__ void __launch_bounds__(256) pass_emit(const u32* __restrict__ buckrec,
        const u32* __restrict__ bcnt, const u32* __restrict__ ubase,
        const float* __restrict__ kern, float4* __restrict__ rows,
        float* __restrict__ feats, int n) {
    __shared__ u32 bm[BPB][WOPAD];
    __shared__ u32 wofW[BPB][BWORDS];     // per-WORD excl unique prefix, j-major (j<<6)|lane
    __shared__ float fl[BPB][FCAP];
    __shared__ float ksc[BPB][8];
    u32 wave = threadIdx.x >> 6, lane = threadIdx.x & 63u;
    u32 bucket = blockIdx.x * BPB + wave;
    u32* B = bm[wave];
    u32* W = wofW[wave];
    float* F = fl[wave];
    #pragma unroll
    for (int j = 0; j < WPL; ++j) B[woidx(lane * WPL + j)] = 0u;
    #pragma unroll
    for (u32 j = lane; j < FCAP; j += 64u) F[j] = 0.f;
    if (lane < 8u) ksc[wave][lane] = (float)(1u << lane) * kern[lane];
    wsync();
    u32 start = bucket * (u32)CAP;
    u32 cnt = bcnt[bucket];
    u32 recv[RECV];
    #pragma unroll
    for (int k = 0; k < RECV; ++k) {
        u32 idx = (u32)k * 64u + lane;
        if (idx < cnt) {
            u32 rec = buckrec[start + idx];
            recv[k] = rec;
            u32 lk = (rec >> 3) & LMASK;
            atomicOr(&B[woidx(lk >> 5)], 1u << (lk & 31u));
        }
    }
    wsync();
    u32 wv[WPL]; u32 pc[WPL]; u32 sum = 0;
    #pragma unroll
    for (int j = 0; j < WPL; ++j) {
        wv[j] = B[woidx(lane * WPL + j)];
        pc[j] = __popc(wv[j]);
        sum += pc[j];
    }
    u32 incl = sum;
    #pragma unroll
    for (int d = 1; d < 64; d <<= 1) {
        u32 tt = __shfl_up(incl, d);
        if ((int)lane >= d) incl += tt;
    }
    u32 lex = incl - sum;                 // lane-exclusive unique offset in bucket
    u32 uc = __shfl(incl, 63);            // bucket total uniques
    {
        u32 r = lex;
        #pragma unroll
        for (int j = 0; j < WPL; ++j) { W[((u32)j << 6) | lane] = r; r += pc[j]; }
    }
    wsync();
    u32 base = ubase[bucket];
    bool lds_ok = (uc <= FCAP);
    if (!lds_ok) {                        // rare: zero own global window first
        for (u32 j = lane; j < uc; j += 64u) feats[base + j] = 0.f;
        asm volatile("s_waitcnt vmcnt(0)" ::: "memory");
    }
    #pragma unroll
    for (int k = 0; k < RECV; ++k) {
        u32 idx = (u32)k * 64u + lane;
        if (idx < cnt) {
            u32 rec = recv[k];
            float contrib = ksc[wave][rec & 7u];
            u32 lk = (rec >> 3) & LMASK;
            u32 w = lk >> 5, bit = lk & 31u;
            u32 r = W[((w & 7u) << 6) | (w >> 3)]
                  + __popc(B[woidx(w)] & ((1u << bit) - 1u));
            if (lds_ok) atomicAdd(&F[r], contrib);
            else        atomicAdd(&feats[base + r], contrib);
        }
    }
    wsync();
    u32 rank = base + lex;
    u32 keyhi = bucket << LBITS;
    #pragma unroll
    for (int j = 0; j < WPL; ++j) {
        u32 bits = wv[j];
        u32 kb = keyhi | ((lane * (u32)WPL + (u32)j) << 5);
        while (bits) {
            u32 tz = __builtin_ctz(bits);
            bits &= bits - 1u;
            u32 key = kb | tz;
            rows[rank++] = make_float4((float)(key >> 27), (float)(key & 511u),
                                       (float)((key >> 9) & 511u),
                                       (float)((key >> 18) & 511u));
        }
    }
    if (lds_ok) {
        for (u32 j = lane; j < uc; j += 64u) feats[base + j] = F[j];
    }
}

// pad rows AND feats in [U, n): feats is not globally pre-zeroed
__global__ void pad_fill(float4* __restrict__ rows, float* __restrict__ feats,
                         const u32* __restrict__ counter, int n) {
    int i = blockIdx.x * blockDim.x + threadIdx.x;
    if (i < n && (u32)i >= counter[0]) {
        rows[i] = make_float4(-1.f, -1.f, -1.f, -1.f);
        feats[i] = 0.f;
    }
}

extern "C" void kernel_launch(void* const* d_in, const int* in_sizes, int n_in,
                              void* d_out, int out_size, void* d_ws, size_t ws_size,
                              hipStream_t stream) {
    const int n = in_sizes[0] / 4;               // 4,000,000 points
    const int4* coords = (const int4*)d_in[0];
    const float* kern  = (const float*)d_in[1];
    const u32 NT = ((u32)n + TILE_A - 1) / TILE_A;        // 489 tiles
    const u32 G1 = 256 * NT;                               // histmat entries (125184)
    const u32 NB1 = (G1 + SCAN_ELEM - 1) / SCAN_ELEM;      // 62
    const u32 NB3 = (NBUCK + SCAN_ELEM - 1) / SCAN_ELEM;   // 16

    u32* wsp = (u32*)d_ws;
    u32* tmp     = wsp;                    // n  (coarse-ordered records)
    u32* histmat = tmp + n;                // G1 raw per-tile hist
    u32* histex  = histmat + G1;           // G1 scanned bases
    u32* cursor  = histex + G1;            // NBUCK (zeroed in part1 -> counts after part2)
    u32* ucount  = cursor + NBUCK;         // NBUCK raw unique counts
    u32* ubase   = ucount + NBUCK;         // NBUCK scanned bases
    u32* counter = ubase + NBUCK;          // 4
    u32* spart   = counter + 4;            // 256
    u32* linrec  = spart + 256;            // n (dead after part1)
    u32* buckrec = linrec;                 // NBUCK*CAP windows, overlaps linrec

    float4* rows  = (float4*)d_out;                              // n rows
    float*  feats = (float*)((char*)d_out + (size_t)n * 16);     // n fp32

    phase_a<<<NT, 256, 0, stream>>>(coords, linrec, histmat, n, NT);
    scan_reduce<<<NB1, 256, 0, stream>>>(histmat, spart, G1);
    scan_apply2<<<NB1, 256, 0, stream>>>(histmat, histex, spart, G1, NB1, (u32*)nullptr);
    part1<<<NT, 256, 0, stream>>>(linrec, histex, tmp, cursor, n, NT);
    part2<<<256 * S2, 256, 0, stream>>>(tmp, histex, cursor, buckrec, n, NT);
    pass_count<<<NBUCK / BPB, 256, 0, stream>>>(buckrec, cursor, ucount, n);
    scan_reduce<<<NB3, 256, 0, stream>>>(ucount, spart, NBUCK);
    scan_apply2<<<NB3, 256, 0, stream>>>(ucount, ubase, spart, NBUCK, NB3, counter);
    pass_emit<<<NBUCK / BPB, 256, 0, stream>>>(buckrec, cursor, ubase, kern,
                                               rows, feats, n);
    pad_fill<<<((u32)n + 255) / 256, 256, 0, stream>>>(rows, feats, counter, n);
}

// Round 10
// 213.849 us; speedup vs baseline: 1.3916x; 1.0656x over previous
//
#include <hip/hip_runtime.h>
#include <stdint.h>

typedef unsigned int u32;
typedef unsigned long long u64;

// key = ((b*512 + z/2)*512 + y/2)*512 + x/2  in [0, 2^29)
// rec = (key<<3)|off. coarse = rec>>24 (8b), fine = (rec>>17)&127 (7b),
// bucket = key>>14 = rec>>17 (15b), local key = key & 0x3FFF (14b).
#define LBITS  14
#define LMASK  ((1u << LBITS) - 1u)
#define NBUCK  (1u << (29 - LBITS))      // 32768 fine buckets
#define BWORDS (1u << (LBITS - 5))       // 512 u32 bitmap words / bucket
#define WPL    (BWORDS / 64)             // 8 words per lane (one prefix group)
#define WOPAD  (BWORDS + BWORDS / 32)    // +1 word per 32 -> conflict-free strided access
#define FCAP   192                       // LDS feats slots per bucket (mean uc ~122)
#define BPB    4                         // buckets (waves) per 256-thr block
#define TILE_A 4096                      // part1f tile (16 rec/thread) - 8 blocks/CU
#define RPT    (TILE_A / 256)            // records per thread in part1f (16)
#define CCAP   16384                     // fixed tmp region per coarse bin (mean 15625, +6sigma)
#define S2     4                         // chunks per coarse bucket in part2
#define CAP2   4608                      // part2 LDS stage capacity (chunk ~3906, +11sigma)
#define RPT2   (CAP2 / 256)              // 18
#define RECV   4                         // pass_emit register-cached records/lane (256>=CAP)
#define CAP    224                       // fixed buckrec window per bucket (max cnt ~172)
#define SCAN_ELEM 2048

__device__ __forceinline__ u32 woidx(u32 w) { return w + (w >> 5); }

// wave64 is lockstep on CDNA: intra-wave LDS producer->consumer needs only a
// drained LDS counter, not a block barrier.
__device__ __forceinline__ void wsync() {
    asm volatile("s_waitcnt lgkmcnt(0)" ::: "memory");
}

__device__ __forceinline__ u32 make_key(int4 c) {
    return ((((u32)c.x * 512u + ((u32)c.w >> 1)) * 512u + ((u32)c.z >> 1)) * 512u)
           + ((u32)c.y >> 1);
}

// ---- tiny init: zero the padded coarse-reservation counters
__global__ void zero1(u32* __restrict__ p, u32 g) {
    u32 i = blockIdx.x * 256u + threadIdx.x;
    if (i < g) p[i] = 0u;
}

// ---- part1f: coords -> rec, block hist, bulk reserve in padded coarse counters,
// LDS-stage, coalesced write to fixed coarse regions. Also zeroes bucket cursors.
__global__ void __launch_bounds__(256) part1f(const int4* __restrict__ coords,
        u32* __restrict__ ccur, u32* __restrict__ tmp,
        u32* __restrict__ cursor, int n) {
    __shared__ u32 stage[TILE_A];
    __shared__ u32 lcur[256];
    __shared__ u32 gb[256];
    __shared__ u32 wtot[4];
    u32 t = threadIdx.x, wave = t >> 6, lane = t & 63u;
    if (blockIdx.x < 128u) cursor[blockIdx.x * 256u + t] = 0u;  // NBUCK fine cursors
    u32 base = blockIdx.x * TILE_A;
    u32 m = min((u32)TILE_A, (u32)n - base);
    lcur[t] = 0u;
    __syncthreads();
    u32 recv[RPT];
    #pragma unroll
    for (int k = 0; k < RPT; ++k) {
        u32 j = (u32)k * 256u + t;
        if (j < m) {
            int4 c = coords[base + j];
            u32 key = make_key(c);
            u32 off = ((u32)c.y & 1u) | (((u32)c.z & 1u) << 1) | (((u32)c.w & 1u) << 2);
            u32 rec = (key << 3) | off;
            recv[k] = rec;
            atomicAdd(&lcur[rec >> 24], 1u);
        }
    }
    __syncthreads();
    // 256-bin exclusive scan: wave-local prefix + cross-wave offset
    u32 v = lcur[t];
    u32 incl = v;
    #pragma unroll
    for (int d = 1; d < 64; d <<= 1) {
        u32 x = __shfl_up(incl, d);
        if ((int)lane >= d) incl += x;
    }
    if (lane == 63u) wtot[wave] = incl;
    __syncthreads();
    u32 off = (wave > 0u ? wtot[0] : 0u) + (wave > 1u ? wtot[1] : 0u)
            + (wave > 2u ? wtot[2] : 0u);
    u32 excl = off + incl - v;
    // bulk reserve: one atomic per (block,bin); counters padded to own 64B line
    u32 gbase = atomicAdd(&ccur[t * 16u], v);
    lcur[t] = excl;                        // local place cursor
    gb[t] = (t << 14) + gbase - excl;      // dst = c*CCAP + gbase + (stage_idx - excl)
    __syncthreads();
    #pragma unroll
    for (int k = 0; k < RPT; ++k) {
        u32 j = (u32)k * 256u + t;
        if (j < m) {
            u32 rec = recv[k];
            u32 pos = atomicAdd(&lcur[rec >> 24], 1u);
            stage[pos] = rec;
        }
    }
    __syncthreads();
    for (u32 j = t; j < m; j += 256u) {
        u32 rec = stage[j];
        tmp[gb[rec >> 24] + j] = rec;      // runs of ~16 -> coalesced
    }
}

// ---- scan step 1: per-chunk raw sums ----
__global__ void scan_reduce(const u32* __restrict__ data, u32* __restrict__ partial, u32 G) {
    __shared__ u32 s[256];
    u32 t = threadIdx.x;
    u32 base = blockIdx.x * SCAN_ELEM + t * 8u;
    u32 sum = 0;
    #pragma unroll
    for (int j = 0; j < 8; ++j) { u32 idx = base + j; if (idx < G) sum += data[idx]; }
    s[t] = sum; __syncthreads();
    for (int d = 128; d > 0; d >>= 1) { if ((int)t < d) s[t] += s[t + d]; __syncthreads(); }
    if (t == 0) partial[blockIdx.x] = s[0];
}

// ---- scan step 2: apply with inline top-level reduction of raw partials ----
__global__ void scan_apply2(const u32* __restrict__ data, u32* __restrict__ out,
                            const u32* __restrict__ partial, u32 G, u32 NB,
                            u32* __restrict__ total) {
    __shared__ u32 s[256];
    __shared__ u32 pb[2];
    u32 t = threadIdx.x;
    u32 p = (t < NB) ? partial[t] : 0u;
    u32 pbef = (t < blockIdx.x) ? p : 0u;
    s[t] = pbef; __syncthreads();
    for (int d = 128; d > 0; d >>= 1) { if ((int)t < d) s[t] += s[t + d]; __syncthreads(); }
    if (t == 0) pb[0] = s[0];
    __syncthreads();
    if (total) {
        s[t] = p; __syncthreads();
        for (int d = 128; d > 0; d >>= 1) { if ((int)t < d) s[t] += s[t + d]; __syncthreads(); }
        if (t == 0) pb[1] = s[0];
        __syncthreads();
        if (blockIdx.x == NB - 1u && t == 0u) total[0] = pb[1];
    }
    u32 base = blockIdx.x * SCAN_ELEM + t * 8u;
    u32 v[8]; u32 sum = 0;
    #pragma unroll
    for (int j = 0; j < 8; ++j) {
        u32 idx = base + j;
        v[j] = (idx < G) ? data[idx] : 0u;
        sum += v[j];
    }
    s[t] = sum; __syncthreads();
    for (int d = 1; d < 256; d <<= 1) {
        u32 add = (t >= (u32)d) ? s[t - d] : 0u;
        __syncthreads(); s[t] += add; __syncthreads();
    }
    u32 run = s[t] - sum + pb[0];
    #pragma unroll
    for (int j = 0; j < 8; ++j) {
        u32 idx = base + j;
        if (idx < G) { u32 x = v[j]; out[idx] = run; run += x; }
    }
}

// ---- part2: fine scatter into fixed per-bucket windows; bulk atomic reserve
__global__ void __launch_bounds__(256) part2(const u32* __restrict__ tmp,
        const u32* __restrict__ ccur, u32* __restrict__ cursor,
        u32* __restrict__ buckrec, int n) {
    __shared__ u32 stage[CAP2];
    __shared__ u32 lcur[128];
    __shared__ u32 dstb[128];
    __shared__ u32 wtot[2];
    u32 t = threadIdx.x, lane = t & 63u;
    u32 c = blockIdx.x / S2, s = blockIdx.x % S2;
    u32 cs = c << 14;                       // c * CCAP
    u32 L = ccur[c * 16u];                  // final coarse count
    u32 lo = cs + L * s / S2, hi = cs + L * (s + 1u) / S2;
    u32 cnt = hi - lo;
    if (cnt <= (u32)CAP2) {
        if (t < 128u) lcur[t] = 0u;
        __syncthreads();
        u32 recv[RPT2];
        #pragma unroll
        for (int k = 0; k < RPT2; ++k) {
            u32 j = (u32)k * 256u + t;
            if (j < cnt) {
                u32 rec = tmp[lo + j];
                recv[k] = rec;
                atomicAdd(&lcur[(rec >> 17) & 127u], 1u);
            }
        }
        __syncthreads();
        u32 v = 0, incl = 0;
        if (t < 128u) {
            v = lcur[t];
            incl = v;
            #pragma unroll
            for (int d = 1; d < 64; d <<= 1) {
                u32 x = __shfl_up(incl, d);
                if ((int)lane >= d) incl += x;
            }
            if (lane == 63u) wtot[t >> 6] = incl;
        }
        __syncthreads();
        if (t < 128u) {
            u32 off = (t >= 64u) ? wtot[0] : 0u;
            u32 excl = off + incl - v;
            u32 bucket = (c << 7) | t;
            u32 gbase = atomicAdd(&cursor[bucket], v);   // reserve v slots (one per bin)
            lcur[t] = excl;
            dstb[t] = bucket * (u32)CAP + gbase - excl;
        }
        __syncthreads();
        #pragma unroll
        for (int k = 0; k < RPT2; ++k) {
            u32 j = (u32)k * 256u + t;
            if (j < cnt) {
                u32 rec = recv[k];
                u32 pos = atomicAdd(&lcur[(rec >> 17) & 127u], 1u);
                stage[pos] = rec;
            }
        }
        __syncthreads();
        for (u32 j = t; j < cnt; j += 256u) {
            u32 rec = stage[j];
            buckrec[dstb[(rec >> 17) & 127u] + j] = rec;   // runs ~30 -> coalesced
        }
    } else {
        // fallback: direct atomic scatter into windows (rare)
        for (u32 i = lo + t; i < hi; i += 256u) {
            u32 rec = tmp[i];
            u32 b = rec >> 17;
            u32 pos = atomicAdd(&cursor[b], 1u);
            buckrec[b * (u32)CAP + pos] = rec;
        }
    }
}

// ---- one wave per fine bucket, no block barriers: bitmap -> unique count
__global__ void __launch_bounds__(256) pass_count(const u32* __restrict__ buckrec,
        const u32* __restrict__ bcnt, u32* __restrict__ ucount, int n) {
    __shared__ u32 bm[BPB][WOPAD];
    u32 wave = threadIdx.x >> 6, lane = threadIdx.x & 63u;
    u32 bucket = blockIdx.x * BPB + wave;
    u32* B = bm[wave];
    #pragma unroll
    for (int j = 0; j < WPL; ++j) B[woidx(lane * WPL + j)] = 0u;
    wsync();
    u32 start = bucket * (u32)CAP;
    u32 end = start + bcnt[bucket];
    for (u32 i = start + lane; i < end; i += 64u) {
        u32 lk = (buckrec[i] >> 3) & LMASK;
        atomicOr(&B[woidx(lk >> 5)], 1u << (lk & 31u));
    }
    wsync();
    u32 sum = 0;
    #pragma unroll
    for (int j = 0; j < WPL; ++j) sum += __popc(B[woidx(lane * WPL + j)]);
    #pragma unroll
    for (int d = 1; d < 64; d <<= 1) sum += __shfl_xor(sum, d);
    if (lane == 0u) ucount[bucket] = sum;
}

// ---- one wave per fine bucket, no block barriers: rank table + feats + emit
__global__ void __launch_bounds__(256) pass_emit(const u32* __restrict__ buckrec,
        const u32* __restrict__ bcnt, const u32* __restrict__ ubase,
        const float* __restrict__ kern, float4* __restrict__ rows,
        float* __restrict__ feats, int n) {
    __shared__ u32 bm[BPB][WOPAD];
    __shared__ u32 wofW[BPB][BWORDS];     // per-WORD excl unique prefix, j-major (j<<6)|lane
    __shared__ float fl[BPB][FCAP];
    __shared__ float ksc[BPB][8];
    u32 wave = threadIdx.x >> 6, lane = threadIdx.x & 63u;
    u32 bucket = blockIdx.x * BPB + wave;
    u32* B = bm[wave];
    u32* W = wofW[wave];
    float* F = fl[wave];
    #pragma unroll
    for (int j = 0; j < WPL; ++j) B[woidx(lane * WPL + j)] = 0u;
    #pragma unroll
    for (u32 j = lane; j < FCAP; j += 64u) F[j] = 0.f;
    if (lane < 8u) ksc[wave][lane] = (float)(1u << lane) * kern[lane];
    wsync();
    u32 start = bucket * (u32)CAP;
    u32 cnt = bcnt[bucket];
    u32 recv[RECV];
    #pragma unroll
    for (int k = 0; k < RECV; ++k) {
        u32 idx = (u32)k * 64u + lane;
        if (idx < cnt) {
            u32 rec = buckrec[start + idx];
            recv[k] = rec;
            u32 lk = (rec >> 3) & LMASK;
            atomicOr(&B[woidx(lk >> 5)], 1u << (lk & 31u));
        }
    }
    wsync();
    u32 wv[WPL]; u32 pc[WPL]; u32 sum = 0;
    #pragma unroll
    for (int j = 0; j < WPL; ++j) {
        wv[j] = B[woidx(lane * WPL + j)];
        pc[j] = __popc(wv[j]);
        sum += pc[j];
    }
    u32 incl = sum;
    #pragma unroll
    for (int d = 1; d < 64; d <<= 1) {
        u32 tt = __shfl_up(incl, d);
        if ((int)lane >= d) incl += tt;
    }
    u32 lex = incl - sum;                 // lane-exclusive unique offset in bucket
    u32 uc = __shfl(incl, 63);            // bucket total uniques
    {
        u32 r = lex;
        #pragma unroll
        for (int j = 0; j < WPL; ++j) { W[((u32)j << 6) | lane] = r; r += pc[j]; }
    }
    wsync();
    u32 base = ubase[bucket];
    bool lds_ok = (uc <= FCAP);
    if (!lds_ok) {                        // rare: zero own global window first
        for (u32 j = lane; j < uc; j += 64u) feats[base + j] = 0.f;
        asm volatile("s_waitcnt vmcnt(0)" ::: "memory");
    }
    #pragma unroll
    for (int k = 0; k < RECV; ++k) {
        u32 idx = (u32)k * 64u + lane;
        if (idx < cnt) {
            u32 rec = recv[k];
            float contrib = ksc[wave][rec & 7u];
            u32 lk = (rec >> 3) & LMASK;
            u32 w = lk >> 5, bit = lk & 31u;
            u32 r = W[((w & 7u) << 6) | (w >> 3)]
                  + __popc(B[woidx(w)] & ((1u << bit) - 1u));
            if (lds_ok) atomicAdd(&F[r], contrib);
            else        atomicAdd(&feats[base + r], contrib);
        }
    }
    wsync();
    u32 rank = base + lex;
    u32 keyhi = bucket << LBITS;
    #pragma unroll
    for (int j = 0; j < WPL; ++j) {
        u32 bits = wv[j];
        u32 kb = keyhi | ((lane * (u32)WPL + (u32)j) << 5);
        while (bits) {
            u32 tz = __builtin_ctz(bits);
            bits &= bits - 1u;
            u32 key = kb | tz;
            rows[rank++] = make_float4((float)(key >> 27), (float)(key & 511u),
                                       (float)((key >> 9) & 511u),
                                       (float)((key >> 18) & 511u));
        }
    }
    if (lds_ok) {
        for (u32 j = lane; j < uc; j += 64u) feats[base + j] = F[j];
    }
}

// pad rows AND feats in [U, n): feats is not globally pre-zeroed
__global__ void pad_fill(float4* __restrict__ rows, float* __restrict__ feats,
                         const u32* __restrict__ counter, int n) {
    int i = blockIdx.x * blockDim.x + threadIdx.x;
    if (i < n && (u32)i >= counter[0]) {
        rows[i] = make_float4(-1.f, -1.f, -1.f, -1.f);
        feats[i] = 0.f;
    }
}

extern "C" void kernel_launch(void* const* d_in, const int* in_sizes, int n_in,
                              void* d_out, int out_size, void* d_ws, size_t ws_size,
                              hipStream_t stream) {
    const int n = in_sizes[0] / 4;               // 4,000,000 points
    const int4* coords = (const int4*)d_in[0];
    const float* kern  = (const float*)d_in[1];
    const u32 NT = ((u32)n + TILE_A - 1) / TILE_A;        // 977 tiles
    const u32 NB3 = (NBUCK + SCAN_ELEM - 1) / SCAN_ELEM;   // 16

    u32* wsp = (u32*)d_ws;
    u32* tmp     = wsp;                    // 256*CCAP (fixed coarse regions)
    u32* ccur    = tmp + 256 * CCAP;       // 256*16 padded coarse counters (1/64B line)
    u32* cursor  = ccur + 256 * 16;        // NBUCK (zeroed in part1f -> counts after part2)
    u32* ucount  = cursor + NBUCK;         // NBUCK raw unique counts
    u32* ubase   = ucount + NBUCK;         // NBUCK scanned bases
    u32* counter = ubase + NBUCK;          // 4
    u32* spart   = counter + 4;            // 256
    u32* buckrec = spart + 256;            // NBUCK*CAP windows

    float4* rows  = (float4*)d_out;                              // n rows
    float*  feats = (float*)((char*)d_out + (size_t)n * 16);     // n fp32

    zero1<<<16, 256, 0, stream>>>(ccur, 256 * 16);
    part1f<<<NT, 256, 0, stream>>>(coords, ccur, tmp, cursor, n);
    part2<<<256 * S2, 256, 0, stream>>>(tmp, ccur, cursor, buckrec, n);
    pass_count<<<NBUCK / BPB, 256, 0, stream>>>(buckrec, cursor, ucount, n);
    scan_reduce<<<NB3, 256, 0, stream>>>(ucount, spart, NBUCK);
    scan_apply2<<<NB3, 256, 0, stream>>>(ucount, ubase, spart, NBUCK, NB3, counter);
    pass_emit<<<NBUCK / BPB, 256, 0, stream>>>(buckrec, cursor, ubase, kern,
                                               rows, feats, n);
    pad_fill<<<((u32)n + 255) / 256, 256, 0, stream>>>(rows, feats, counter, n);
}